// Round 2
// baseline (449.594 us; speedup 1.0000x reference)
//
#include <hip/hip_runtime.h>

#define HDIM 1024
#define TDIM 17
#define BDIM 64
#define SDIM 512
#define NROWS (BDIM * SDIM) /* 32768 */

// ---------------------------------------------------------------------------
// Kernel 1: feats = x @ W^T + b.  16 lanes per row (K split 16-way,
// interleaved so each instruction's addresses are 256B-contiguous segments),
// 4 rows per wave, 256 threads/block -> 16 rows/block, 2048 blocks.
// Cross-lane shfl_xor reduction over the 16-lane group; bias fused.
// ---------------------------------------------------------------------------
__global__ __launch_bounds__(256) void gemm_kernel(
    const float* __restrict__ x, const float* __restrict__ W,
    const float* __restrict__ b, float* __restrict__ feats) {
  int tid = threadIdx.x;
  int sub = tid & 15;        // K-phase within row
  int rowLocal = tid >> 4;   // 0..15
  int row = blockIdx.x * 16 + rowLocal;
  const float* xr = x + (size_t)row * HDIM;
  float acc[TDIM];
#pragma unroll
  for (int t = 0; t < TDIM; ++t) acc[t] = 0.f;
#pragma unroll
  for (int c = 0; c < 16; ++c) {
    float4 xv = *(const float4*)(xr + c * 64 + sub * 4);
#pragma unroll
    for (int t = 0; t < TDIM; ++t) {
      float4 wv = *(const float4*)(W + t * HDIM + c * 64 + sub * 4);
      float a = acc[t];
      a = fmaf(xv.x, wv.x, a);
      a = fmaf(xv.y, wv.y, a);
      a = fmaf(xv.z, wv.z, a);
      a = fmaf(xv.w, wv.w, a);
      acc[t] = a;
    }
  }
  // reduce across the 16-lane group (xor masks < 16 stay in-group)
#pragma unroll
  for (int t = 0; t < TDIM; ++t) {
#pragma unroll
    for (int m = 1; m < 16; m <<= 1) acc[t] += __shfl_xor(acc[t], m, 64);
  }
  // lane `sub` writes tag t=sub (coalesced 64B run); lane 0 also writes t=16
  float val = acc[0];
#pragma unroll
  for (int t = 1; t < 16; ++t) val = (sub == t) ? acc[t] : val;
  feats[(size_t)row * TDIM + sub] = val + b[sub];
  if (sub == 0) feats[(size_t)row * TDIM + 16] = acc[16] + b[16];
}

// ---------------------------------------------------------------------------
// Kernel 2: Viterbi forward + backtrace. One 64-thread block per batch.
// Scores live in SGPRs via v_readlane broadcast (no LDS round-trip in the
// serial chain). Lane j owns transition column j; bp bytes in LDS.
// ---------------------------------------------------------------------------
__global__ __launch_bounds__(64) void viterbi_kernel(
    const float* __restrict__ feats, const float* __restrict__ trans,
    const float* __restrict__ start_t, const float* __restrict__ end_t,
    const int* __restrict__ nwords, float* __restrict__ tags_out) {
  __shared__ __align__(16) float s_feats[SDIM * TDIM];
  __shared__ unsigned char s_bp[SDIM * TDIM];
  __shared__ unsigned char s_tags[SDIM];
  int b = blockIdx.x;
  int lane = threadIdx.x;
  const float* fb = feats + (size_t)b * SDIM * TDIM;
  {  // stage feats: 8704 floats = 2176 float4, coalesced
    const float4* src = (const float4*)fb;
    float4* dst = (float4*)s_feats;
    for (int i = lane; i < (SDIM * TDIM) / 4; i += 64) dst[i] = src[i];
  }
  __syncthreads();

  int nw = nwords[b];
  if (nw < 1) nw = 1;
  if (nw > SDIM) nw = SDIM;
  int jj = lane < TDIM ? lane : TDIM - 1;

  float tcol[TDIM];  // transitions column jj (lane-private)
#pragma unroll
  for (int i = 0; i < TDIM; ++i) tcol[i] = trans[i * TDIM + jj];

  float s[TDIM];  // scores, replicated (becomes SGPR-held after step 1)
#pragma unroll
  for (int i = 0; i < TDIM; ++i) s[i] = start_t[i] + s_feats[i];

  const float* fptr = s_feats + TDIM + jj;  // feats[t=1][jj]
  float fcur = *fptr;

  for (int t = 1; t < nw; ++t) {
    float v[TDIM];
    int ix[TDIM];
#pragma unroll
    for (int i = 0; i < TDIM; ++i) {
      v[i] = s[i] + tcol[i];
      ix[i] = i;
    }
    // first-max argmax tree (strict > keeps lower index = jnp.argmax)
#define CMB(a, c)    \
  if (v[c] > v[a]) { \
    v[a] = v[c];     \
    ix[a] = ix[c];   \
  }
    CMB(0, 1) CMB(2, 3) CMB(4, 5) CMB(6, 7)
    CMB(8, 9) CMB(10, 11) CMB(12, 13) CMB(14, 15)
    CMB(0, 2) CMB(4, 6) CMB(8, 10) CMB(12, 14)
    CMB(0, 4) CMB(8, 12)
    CMB(0, 8)
    CMB(0, 16)
#undef CMB
    float ns = v[0] + fcur;
    if (lane < TDIM) s_bp[t * TDIM + lane] = (unsigned char)ix[0];
    fptr += TDIM;
    fcur = (t + 1 < SDIM) ? *fptr : 0.f;
    // broadcast: lane i's ns -> SGPR; next step reads v_add v, s, v
#pragma unroll
    for (int i = 0; i < TDIM; ++i)
      s[i] = __uint_as_float(
          (unsigned)__builtin_amdgcn_readlane((int)__float_as_uint(ns), i));
  }
  __syncthreads();  // bp visible

  // last_tag = argmax(score + end_trans), first-max
  float bv = s[0] + end_t[0];
  int bi = 0;
#pragma unroll
  for (int j = 1; j < TDIM; ++j) {
    float c = s[j] + end_t[j];
    if (c > bv) {
      bv = c;
      bi = j;
    }
  }
  // backtrace (all lanes redundantly; uniform LDS broadcast reads)
  int tag = bi;
  s_tags[nw - 1] = (unsigned char)tag;
  for (int t = nw - 1; t >= 1; --t) {
    tag = s_bp[t * TDIM + tag];
    s_tags[t - 1] = (unsigned char)tag;
  }
  __syncthreads();
  float* ob = tags_out + (size_t)b * SDIM;
  for (int t = lane; t < SDIM; t += 64)
    ob[t] = (t < nw) ? (float)s_tags[t] : 0.f;
}

// ---------------------------------------------------------------------------
extern "C" void kernel_launch(void* const* d_in, const int* in_sizes, int n_in,
                              void* d_out, int out_size, void* d_ws,
                              size_t ws_size, hipStream_t stream) {
  const float* x = (const float*)d_in[0];
  const float* W = (const float*)d_in[1];
  const float* b = (const float*)d_in[2];
  const float* trans = (const float*)d_in[3];
  const float* start_t = (const float*)d_in[4];
  const float* end_t = (const float*)d_in[5];
  const int* nwords = (const int*)d_in[6];
  float* out = (float*)d_out;
  float* tags_out = out;           // (B, S) floats
  float* feats_out = out + NROWS;  // (B, S, T) floats

  gemm_kernel<<<NROWS / 16, 256, 0, stream>>>(x, W, b, feats_out);
  viterbi_kernel<<<BDIM, 64, 0, stream>>>(feats_out, trans, start_t, end_t,
                                          nwords, tags_out);
}

// Round 3
// 373.062 us; speedup vs baseline: 1.2051x; 1.2051x over previous
//
#include <hip/hip_runtime.h>

#define HDIM 1024
#define TDIM 17
#define BDIM 64
#define SDIM 512
#define NROWS (BDIM * SDIM) /* 32768 */

// ---------------------------------------------------------------------------
// Kernel 1: feats = x @ W^T + b.  16-way K-split per row, 4 rows per thread
// (W loads amortized over 4 rows -> W cache traffic /4). 256 threads = 64
// rows/block, 512 blocks = 2048 waves. Cross-lane shfl_xor reduce (16-lane
// groups), bias fused, coalesced stores.
// ---------------------------------------------------------------------------
__global__ __launch_bounds__(256) void gemm_kernel(
    const float* __restrict__ x, const float* __restrict__ W,
    const float* __restrict__ b, float* __restrict__ feats) {
  int tid = threadIdx.x;
  int sub = tid & 15;  // K-phase
  int g = tid >> 4;    // row-group 0..15
  int row0 = blockIdx.x * 64 + g * 4;
  const float* xr = x + (size_t)row0 * HDIM;
  float acc[4][TDIM];
#pragma unroll
  for (int r = 0; r < 4; ++r)
#pragma unroll
    for (int t = 0; t < TDIM; ++t) acc[r][t] = 0.f;
#pragma unroll 2
  for (int c = 0; c < 16; ++c) {
    float4 xv[4];
#pragma unroll
    for (int r = 0; r < 4; ++r)
      xv[r] = *(const float4*)(xr + r * HDIM + c * 64 + sub * 4);
#pragma unroll
    for (int t = 0; t < TDIM; ++t) {
      float4 wv = *(const float4*)(W + t * HDIM + c * 64 + sub * 4);
#pragma unroll
      for (int r = 0; r < 4; ++r) {
        float a = acc[r][t];
        a = fmaf(xv[r].x, wv.x, a);
        a = fmaf(xv[r].y, wv.y, a);
        a = fmaf(xv[r].z, wv.z, a);
        a = fmaf(xv[r].w, wv.w, a);
        acc[r][t] = a;
      }
    }
  }
  // reduce across the 16-lane K-group (xor masks < 16 stay in-group)
#pragma unroll
  for (int r = 0; r < 4; ++r)
#pragma unroll
    for (int t = 0; t < TDIM; ++t) {
#pragma unroll
      for (int m = 1; m < 16; m <<= 1)
        acc[r][t] += __shfl_xor(acc[r][t], m, 64);
    }
  // lane `sub` writes tag t=sub (64B contiguous run); lane 0 also writes t=16
#pragma unroll
  for (int r = 0; r < 4; ++r) {
    float val = acc[r][0];
#pragma unroll
    for (int t = 1; t < 16; ++t) val = (sub == t) ? acc[r][t] : val;
    feats[(size_t)(row0 + r) * TDIM + sub] = val + b[sub];
    if (sub == 0) feats[(size_t)(row0 + r) * TDIM + 16] = acc[r][16] + b[16];
  }
}

// ---------------------------------------------------------------------------
// Kernel 2: Viterbi forward + backtrace. One 64-thread block per batch.
// feats transposed in LDS [tag][t] (stride 516 floats, b128-aligned),
// prefetched 8 steps ahead; scores broadcast via v_readlane (SGPR-held);
// CMB tree is branch-free (cndmask); bp bytes packed, one ds_write_b64 per
// 8 steps into transposed [tag][t] layout (stride 520B).
// ---------------------------------------------------------------------------
#define FSTRIDE 516
#define BPSTRIDE 520

__global__ __launch_bounds__(64) void viterbi_kernel(
    const float* __restrict__ feats, const float* __restrict__ trans,
    const float* __restrict__ start_t, const float* __restrict__ end_t,
    const int* __restrict__ nwords, float* __restrict__ tags_out) {
  __shared__ __align__(16) float s_fT[TDIM * FSTRIDE];          // 35.1 KB
  __shared__ __align__(8) unsigned char s_bpT[TDIM * BPSTRIDE]; // 8.8 KB
  __shared__ unsigned char s_tags[SDIM];
  int b = blockIdx.x;
  int lane = threadIdx.x;
  const float* fb = feats + (size_t)b * SDIM * TDIM;
  // transposed staging: [t][j] global -> [j][t] LDS
  for (int i4 = lane; i4 < (SDIM * TDIM) / 4; i4 += 64) {
    float4 v = ((const float4*)fb)[i4];
    int base = i4 * 4;
    float vv[4] = {v.x, v.y, v.z, v.w};
#pragma unroll
    for (int e = 0; e < 4; ++e) {
      int idx = base + e;
      s_fT[(idx % TDIM) * FSTRIDE + (idx / TDIM)] = vv[e];
    }
  }
  __syncthreads();

  int nw = nwords[b];
  if (nw < 1) nw = 1;
  if (nw > SDIM) nw = SDIM;
  int jj = lane < TDIM ? lane : TDIM - 1;

  float tcol[TDIM];
#pragma unroll
  for (int i = 0; i < TDIM; ++i) tcol[i] = trans[i * TDIM + jj];

  float s[TDIM];  // wave-uniform (SGPR-held after first broadcast)
#pragma unroll
  for (int i = 0; i < TDIM; ++i) s[i] = start_t[i] + s_fT[i * FSTRIDE];

  // feats chunk registers: fc = current 8 steps, fn = next 8
  float fc[8], fn[8];
  {
    float4 a = *(const float4*)&s_fT[jj * FSTRIDE];
    float4 c = *(const float4*)&s_fT[jj * FSTRIDE + 4];
    fc[0] = a.x; fc[1] = a.y; fc[2] = a.z; fc[3] = a.w;
    fc[4] = c.x; fc[5] = c.y; fc[6] = c.z; fc[7] = c.w;
  }

  for (int t0 = 0; t0 < nw; t0 += 8) {
    int tn = (t0 + 8 < SDIM) ? t0 + 8 : t0;  // prefetch next chunk
    {
      float4 a = *(const float4*)&s_fT[jj * FSTRIDE + tn];
      float4 c = *(const float4*)&s_fT[jj * FSTRIDE + tn + 4];
      fn[0] = a.x; fn[1] = a.y; fn[2] = a.z; fn[3] = a.w;
      fn[4] = c.x; fn[5] = c.y; fn[6] = c.z; fn[7] = c.w;
    }
    unsigned bpLo = 0, bpHi = 0;
#pragma unroll
    for (int u = 0; u < 8; ++u) {
      int t = t0 + u;
      if (t >= 1 && t < nw) {
        float v[TDIM];
        int ix[TDIM];
#pragma unroll
        for (int i = 0; i < TDIM; ++i) {
          v[i] = s[i] + tcol[i];
          ix[i] = i;
        }
        // branch-free first-max tree (strict > keeps lower idx = jnp.argmax)
#define CMB(a, c)              \
  {                            \
    bool p = v[c] > v[a];      \
    v[a] = p ? v[c] : v[a];    \
    ix[a] = p ? ix[c] : ix[a]; \
  }
        CMB(0, 1) CMB(2, 3) CMB(4, 5) CMB(6, 7)
        CMB(8, 9) CMB(10, 11) CMB(12, 13) CMB(14, 15)
        CMB(0, 2) CMB(4, 6) CMB(8, 10) CMB(12, 14)
        CMB(0, 4) CMB(8, 12)
        CMB(0, 8)
        CMB(0, 16)
#undef CMB
        float ns = v[0] + fc[u];
        unsigned byte = (unsigned)ix[0] << ((u & 3) * 8);
        if (u < 4) bpLo |= byte; else bpHi |= byte;
        // broadcast lane i's ns into wave-uniform (SGPR) s[i]
#pragma unroll
        for (int i = 0; i < TDIM; ++i)
          s[i] = __uint_as_float(
              (unsigned)__builtin_amdgcn_readlane((int)__float_as_uint(ns), i));
      }
    }
    if (lane < TDIM) {
      unsigned long long w = (unsigned long long)bpLo |
                             ((unsigned long long)bpHi << 32);
      *(unsigned long long*)(s_bpT + lane * BPSTRIDE + t0) = w;
    }
#pragma unroll
    for (int u = 0; u < 8; ++u) fc[u] = fn[u];
  }
  __syncthreads();

  // last_tag = argmax(score + end_trans), first-max (uniform work)
  float bv = s[0] + end_t[0];
  int bi = 0;
#pragma unroll
  for (int j = 1; j < TDIM; ++j) {
    float c = s[j] + end_t[j];
    bool p = c > bv;
    bv = p ? c : bv;
    bi = p ? j : bi;
  }
  // backtrace chase (uniform across lanes; LDS broadcast reads)
  int tag = bi;
  s_tags[nw - 1] = (unsigned char)tag;
  for (int t = nw - 1; t >= 1; --t) {
    tag = s_bpT[tag * BPSTRIDE + t];
    s_tags[t - 1] = (unsigned char)tag;
  }
  __syncthreads();
  float* ob = tags_out + (size_t)b * SDIM;
  for (int t = lane; t < SDIM; t += 64)
    ob[t] = (t < nw) ? (float)s_tags[t] : 0.f;
}

// ---------------------------------------------------------------------------
extern "C" void kernel_launch(void* const* d_in, const int* in_sizes, int n_in,
                              void* d_out, int out_size, void* d_ws,
                              size_t ws_size, hipStream_t stream) {
  const float* x = (const float*)d_in[0];
  const float* W = (const float*)d_in[1];
  const float* b = (const float*)d_in[2];
  const float* trans = (const float*)d_in[3];
  const float* start_t = (const float*)d_in[4];
  const float* end_t = (const float*)d_in[5];
  const int* nwords = (const int*)d_in[6];
  float* out = (float*)d_out;
  float* tags_out = out;           // (B, S)
  float* feats_out = out + NROWS;  // (B, S, T)

  gemm_kernel<<<NROWS / 64, 256, 0, stream>>>(x, W, b, feats_out);
  viterbi_kernel<<<BDIM, 64, 0, stream>>>(feats_out, trans, start_t, end_t,
                                          nwords, tags_out);
}

// Round 4
// 370.446 us; speedup vs baseline: 1.2137x; 1.0071x over previous
//
#include <hip/hip_runtime.h>

#define HDIM 1024
#define TDIM 17
#define BDIM 64
#define SDIM 512
#define NROWS (BDIM * SDIM) /* 32768 */

// ---------------------------------------------------------------------------
// Kernel 1: feats = x @ W^T + b.  W staged in LDS in two half-K phases
// (34.8 KB -> 4 blocks/CU). 16-way K-split per row, 4 rows per thread.
// W reads become ds_read_b128 (L1-thrash eliminated); x streams from HBM.
// ---------------------------------------------------------------------------
__global__ __launch_bounds__(256) void gemm_kernel(
    const float* __restrict__ x, const float* __restrict__ W,
    const float* __restrict__ bias, float* __restrict__ feats) {
  __shared__ __align__(16) float sW[TDIM * 512];  // 34816 B
  int tid = threadIdx.x;
  int sub = tid & 15;  // K-phase within row
  int g = tid >> 4;    // row-group 0..15
  int row0 = blockIdx.x * 64 + g * 4;
  const float* xr = x + (size_t)row0 * HDIM;
  float acc[4][TDIM];
#pragma unroll
  for (int r = 0; r < 4; ++r)
#pragma unroll
    for (int t = 0; t < TDIM; ++t) acc[r][t] = 0.f;

  for (int ph = 0; ph < 2; ++ph) {
    if (ph) __syncthreads();  // WAR: previous phase done reading sW
    // stage W[t][ph*512 .. +511]: 2176 float4, 256 threads -> 8.5 each
    for (int i = tid; i < TDIM * 128; i += 256) {
      int t = i >> 7;
      int k = (i & 127) * 4;
      *(float4*)&sW[t * 512 + k] =
          *(const float4*)&W[(size_t)t * HDIM + ph * 512 + k];
    }
    __syncthreads();
#pragma unroll
    for (int c = 0; c < 8; ++c) {
      float4 xv[4];
#pragma unroll
      for (int r = 0; r < 4; ++r)
        xv[r] = *(const float4*)(xr + r * HDIM + ph * 512 + c * 64 + sub * 4);
#pragma unroll
      for (int t = 0; t < TDIM; ++t) {
        float4 wv = *(const float4*)&sW[t * 512 + c * 64 + sub * 4];
#pragma unroll
        for (int r = 0; r < 4; ++r) {
          float a = acc[r][t];
          a = fmaf(xv[r].x, wv.x, a);
          a = fmaf(xv[r].y, wv.y, a);
          a = fmaf(xv[r].z, wv.z, a);
          a = fmaf(xv[r].w, wv.w, a);
          acc[r][t] = a;
        }
      }
    }
  }
  // reduce across the 16-lane K-group (xor masks < 16 stay in-group)
#pragma unroll
  for (int r = 0; r < 4; ++r)
#pragma unroll
    for (int t = 0; t < TDIM; ++t) {
#pragma unroll
      for (int m = 1; m < 16; m <<= 1)
        acc[r][t] += __shfl_xor(acc[r][t], m, 64);
    }
#pragma unroll
  for (int r = 0; r < 4; ++r) {
    float val = acc[r][0];
#pragma unroll
    for (int t = 1; t < 16; ++t) val = (sub == t) ? acc[r][t] : val;
    feats[(size_t)(row0 + r) * TDIM + sub] = val + bias[sub];
    if (sub == 0)
      feats[(size_t)(row0 + r) * TDIM + 16] = acc[r][16] + bias[16];
  }
}

// ---------------------------------------------------------------------------
// Kernel 2: Viterbi. One 64-thread block (1 wave) per batch.
// Forward: scores wave-uniform (SGPR via v_readlane broadcast); max3 tree
// with off-chain exact argmax recovery; main loop branch-free (peeled
// chunk0/tail). Backtrace: bp bytes live in lane j's packed regs via LDS
// chunks; chase = v_readlane(word, tag) + scalar extract (no LDS in chain).
// ---------------------------------------------------------------------------
#define FSTRIDE 516
#define BPSTRIDE 520

__global__ __launch_bounds__(64) void viterbi_kernel(
    const float* __restrict__ feats, const float* __restrict__ trans,
    const float* __restrict__ start_t, const float* __restrict__ end_t,
    const int* __restrict__ nwords, float* __restrict__ tags_out) {
  __shared__ __align__(16) float s_fT[TDIM * FSTRIDE];           // 35.1 KB
  __shared__ __align__(8) unsigned char s_bpT[TDIM * BPSTRIDE];  // 8.8 KB
  __shared__ unsigned char s_tags[SDIM];
  int b = blockIdx.x;
  int lane = threadIdx.x;
  const float* fb = feats + (size_t)b * SDIM * TDIM;
  // transposed staging: [t][j] global -> [j][t] LDS
  for (int i4 = lane; i4 < (SDIM * TDIM) / 4; i4 += 64) {
    float4 v = ((const float4*)fb)[i4];
    int base = i4 * 4;
    float vv[4] = {v.x, v.y, v.z, v.w};
#pragma unroll
    for (int e = 0; e < 4; ++e) {
      int idx = base + e;
      s_fT[(idx % TDIM) * FSTRIDE + (idx / TDIM)] = vv[e];
    }
  }
  __syncthreads();

  int nw = nwords[b];
  if (nw < 1) nw = 1;
  if (nw > SDIM) nw = SDIM;
  int jj = lane < TDIM ? lane : TDIM - 1;

  float tcol[TDIM];
#pragma unroll
  for (int i = 0; i < TDIM; ++i) tcol[i] = trans[i * TDIM + jj];

  float s[TDIM];  // wave-uniform scores (SGPR-held via readlane broadcast)
#pragma unroll
  for (int i = 0; i < TDIM; ++i) s[i] = start_t[i] + s_fT[i * FSTRIDE];

  auto load8 = [&](float* f, int t) {
    float4 a = *(const float4*)&s_fT[jj * FSTRIDE + t];
    float4 c = *(const float4*)&s_fT[jj * FSTRIDE + t + 4];
    f[0] = a.x; f[1] = a.y; f[2] = a.z; f[3] = a.w;
    f[4] = c.x; f[5] = c.y; f[6] = c.z; f[7] = c.w;
  };

  // one Viterbi step: returns backpointer for this lane's column jj
  auto step = [&](float fcu) -> int {
    float v[TDIM];
#pragma unroll
    for (int i = 0; i < TDIM; ++i) v[i] = s[i] + tcol[i];
    float m0 = fmaxf(fmaxf(v[0], v[1]), v[2]);
    float m1 = fmaxf(fmaxf(v[3], v[4]), v[5]);
    float m2 = fmaxf(fmaxf(v[6], v[7]), v[8]);
    float m3 = fmaxf(fmaxf(v[9], v[10]), v[11]);
    float m4 = fmaxf(fmaxf(v[12], v[13]), v[14]);
    float m5 = fmaxf(v[15], v[16]);
    float n0 = fmaxf(fmaxf(m0, m1), m2);
    float n1 = fmaxf(fmaxf(m3, m4), m5);
    float maxv = fmaxf(n0, n1);
    float ns = maxv + fcu;
    // broadcast first: this is the loop-carried critical path
#pragma unroll
    for (int i = 0; i < TDIM; ++i)
      s[i] = __uint_as_float(
          (unsigned)__builtin_amdgcn_readlane((int)__float_as_uint(ns), i));
    // exact first-max recovery (off critical path; feeds only bp store)
    int r = 16;
#pragma unroll
    for (int i = 15; i >= 0; --i) r = (v[i] == maxv) ? i : r;
    return r;
  };

  float fc[8], fn[8];
  load8(fc, 0);
  // ---- chunk 0: steps 1..7 (guarded once) ----
  {
    load8(fn, 8);
    unsigned lo = 0, hi = 0;
#pragma unroll
    for (int u = 1; u < 8; ++u) {
      if (u < nw) {
        int bp = step(fc[u]);
        unsigned by = (unsigned)bp << ((u & 3) * 8);
        if (u < 4) lo |= by; else hi |= by;
      }
    }
    if (lane < TDIM)
      *(unsigned long long*)(s_bpT + lane * BPSTRIDE) =
          (unsigned long long)lo | ((unsigned long long)hi << 32);
#pragma unroll
    for (int u = 0; u < 8; ++u) fc[u] = fn[u];
  }
  // ---- full chunks: branch-free 8-step bodies ----
  int t0 = 8;
  for (; t0 + 8 <= nw; t0 += 8) {
    int tn = (t0 + 8 <= SDIM - 8) ? t0 + 8 : t0;
    load8(fn, tn);
    unsigned lo = 0, hi = 0;
#pragma unroll
    for (int u = 0; u < 8; ++u) {
      int bp = step(fc[u]);
      unsigned by = (unsigned)bp << ((u & 3) * 8);
      if (u < 4) lo |= by; else hi |= by;
    }
    if (lane < TDIM)
      *(unsigned long long*)(s_bpT + lane * BPSTRIDE + t0) =
          (unsigned long long)lo | ((unsigned long long)hi << 32);
#pragma unroll
    for (int u = 0; u < 8; ++u) fc[u] = fn[u];
  }
  // ---- tail chunk (guarded) ----
  if (t0 < nw) {
    unsigned lo = 0, hi = 0;
#pragma unroll
    for (int u = 0; u < 8; ++u) {
      if (t0 + u < nw) {
        int bp = step(fc[u]);
        unsigned by = (unsigned)bp << ((u & 3) * 8);
        if (u < 4) lo |= by; else hi |= by;
      }
    }
    if (lane < TDIM)
      *(unsigned long long*)(s_bpT + lane * BPSTRIDE + t0) =
          (unsigned long long)lo | ((unsigned long long)hi << 32);
  }

  // ---- final argmax ----
  float bv = s[0] + end_t[0];
  int bi = 0;
#pragma unroll
  for (int j = 1; j < TDIM; ++j) {
    float c = s[j] + end_t[j];
    bool p = c > bv;
    bv = p ? c : bv;
    bi = p ? j : bi;
  }
  int tag = __builtin_amdgcn_readfirstlane(bi);

  // ---- backtrace: readlane chase (no LDS in dependency chain) ----
  s_tags[nw - 1] = (unsigned char)tag;  // all lanes, same addr+data
  {
    int tmax = nw - 1;
    int ctop = tmax >> 3;
    unsigned wlo, whi;
    {
      unsigned long long w =
          *(const unsigned long long*)(s_bpT + jj * BPSTRIDE + ctop * 8);
      wlo = (unsigned)w;
      whi = (unsigned)(w >> 32);
    }
    int thi = tmax;
    for (int c = ctop; c >= 0; --c) {
      unsigned nlo = 0, nhi = 0;
      if (c > 0) {  // prefetch next chunk (latency hidden behind 8 steps)
        unsigned long long w =
            *(const unsigned long long*)(s_bpT + jj * BPSTRIDE + (c - 1) * 8);
        nlo = (unsigned)w;
        nhi = (unsigned)(w >> 32);
      }
      int tlo = (c * 8 > 1) ? c * 8 : 1;
      for (int t = thi; t >= tlo; --t) {
        int u = t & 7;
        int rlo = __builtin_amdgcn_readlane((int)wlo, tag);
        int rhi = __builtin_amdgcn_readlane((int)whi, tag);
        int word = (u < 4) ? rlo : rhi;
        tag = (word >> ((u & 3) * 8)) & 0xff;
        s_tags[t - 1] = (unsigned char)tag;
      }
      thi = c * 8 - 1;
      wlo = nlo;
      whi = nhi;
    }
  }
  __syncthreads();
  float* ob = tags_out + (size_t)b * SDIM;
  for (int t = lane; t < SDIM; t += 64)
    ob[t] = (t < nw) ? (float)s_tags[t] : 0.f;
}

// ---------------------------------------------------------------------------
extern "C" void kernel_launch(void* const* d_in, const int* in_sizes, int n_in,
                              void* d_out, int out_size, void* d_ws,
                              size_t ws_size, hipStream_t stream) {
  const float* x = (const float*)d_in[0];
  const float* W = (const float*)d_in[1];
  const float* b = (const float*)d_in[2];
  const float* trans = (const float*)d_in[3];
  const float* start_t = (const float*)d_in[4];
  const float* end_t = (const float*)d_in[5];
  const int* nwords = (const int*)d_in[6];
  float* out = (float*)d_out;
  float* tags_out = out;           // (B, S)
  float* feats_out = out + NROWS;  // (B, S, T)

  gemm_kernel<<<NROWS / 64, 256, 0, stream>>>(x, W, b, feats_out);
  viterbi_kernel<<<BDIM, 64, 0, stream>>>(feats_out, trans, start_t, end_t,
                                          nwords, tags_out);
}